// Round 2
// baseline (206.428 us; speedup 1.0000x reference)
//
#include <hip/hip_runtime.h>

// GraphPooling: B=8, N=3072, D=1024, POOL=3, steps=1024
//  out[b, 2k,   d] = (sum x[b, s..e, d]) / (e-s+1) + 0.006
//  out[b, 2k+1, d] = mean(x[b, 3k:3k+3, d])
//
// Round-9 (resubmit; R1 bench was a GPU-acquisition timeout, no data):
//  - K1: x loads are REGULAR (cached) loads, not nontemporal.
//    Theory: x (96 MB) + Wl (32 MB) fit in the 256 MB Infinity Cache;
//    K3's 4-random-x-rows-per-step gather then hits L3 instead of
//    missing to HBM (~900 cyc). nt_store for `out` kept (never re-read,
//    stays out of L3). Wl/P remain regular stores (re-read by K2/K3).
//  - K2: 64 -> 256 blocks (8 f4-cols x 32 segs of 4 chunks); was using
//    only 25% of CUs.
//  - K3 unchanged, so its counter delta isolates the L3 theory.

constexpr int Bdim  = 8;
constexpr int Nn    = 3072;
constexpr int Dd    = 1024;
constexpr int STEPS = 1024;   // windows
constexpr int CHW   = 8;      // windows per chunk
constexpr int NCH   = 128;    // STEPS / CHW
constexpr int KT    = 2;      // steps per K3 block
constexpr int NKT   = 512;    // STEPS / KT
constexpr int D4    = Dd / 4; // 256 float4 per row
constexpr float EPS = 0.006f;

constexpr size_t WL_E = (size_t)Bdim * STEPS * Dd;        // 32 MB
constexpr size_t P_E  = (size_t)Bdim * NCH * Dd;          //  4 MB

typedef float nat_f4 __attribute__((ext_vector_type(4)));

__device__ __forceinline__ float4 f4add(float4 a, float4 b) {
    return make_float4(a.x + b.x, a.y + b.y, a.z + b.z, a.w + b.w);
}

__device__ __forceinline__ float4 f4sel(bool c, float4 a, float4 b) {
    return make_float4(c ? a.x : b.x, c ? a.y : b.y,
                       c ? a.z : b.z, c ? a.w : b.w);
}

__device__ __forceinline__ void nt_store(float4 v, float4* p) {
    nat_f4 nv = {v.x, v.y, v.z, v.w};
    __builtin_nontemporal_store(nv, reinterpret_cast<nat_f4*>(p));
}

// ---------------- K1: window sums + within-chunk prefix ----------------
__global__ __launch_bounds__(256)
void k1_scan(const float4* __restrict__ x4, float4* __restrict__ out4,
             float4* __restrict__ Wl4, float4* __restrict__ P4) {
    const int t  = threadIdx.x;          // float4 column 0..255
    const int ch = blockIdx.x;           // 0..127
    const int b  = blockIdx.y;           // 0..7
    const int k0 = ch * CHW;
    const int r0 = k0 * 3;

    const float4* xp = x4   + ((size_t)(b * Nn + r0)) * D4 + t;
    float4*       wl = Wl4  + ((size_t)(b * STEPS + k0)) * D4 + t;
    float4*       op = out4 + ((size_t)b * 2 * STEPS) * D4 + t;

    // phase A: issue all 24 loads before any dependent use.
    // REGULAR loads (not nt): deliberately leave x resident in L2/L3 so
    // K3's random row gather hits cache instead of HBM.
    float4 v[3 * CHW];
#pragma unroll
    for (int i = 0; i < 3 * CHW; ++i)
        v[i] = xp[(size_t)i * D4];

    // phase B: window sums
    float4 w[CHW];
#pragma unroll
    for (int wi = 0; wi < CHW; ++wi)
        w[wi] = f4add(f4add(v[3 * wi], v[3 * wi + 1]), v[3 * wi + 2]);

    // phase C: prefix + stores
    float4 run = make_float4(0.f, 0.f, 0.f, 0.f);
#pragma unroll
    for (int wi = 0; wi < CHW; ++wi) {
        wl[(size_t)wi * D4] = run;                      // exclusive prefix
        float4 wm = make_float4(w[wi].x * (1.f / 3.f), w[wi].y * (1.f / 3.f),
                                w[wi].z * (1.f / 3.f), w[wi].w * (1.f / 3.f));
        nt_store(wm, &op[(size_t)(2 * (k0 + wi) + 1) * D4]);
        run = f4add(run, w[wi]);
    }
    P4[((size_t)b * NCH + ch) * D4 + t] = run;
}

// ---------------- K2: 2-level scan of chunk totals -> exclusive prefix O ----
// 256 blocks (was 64): block covers 8 f4-cols; 32 segs x 4 chunks each.
__global__ __launch_bounds__(256)
void k2_chscan(const float4* __restrict__ P4, float4* __restrict__ O4) {
    __shared__ float4 part[8][33];
    const int c   = threadIdx.x & 7;           // f4-col within block tile
    const int seg = threadIdx.x >> 3;          // 0..31 -> 4 chunks each
    const int col = blockIdx.x * 8 + c;
    const int b   = blockIdx.y;

    const float4* p = P4 + (size_t)b * NCH * D4 + col;
    float4 v[4];
    float4 sum = make_float4(0.f, 0.f, 0.f, 0.f);
#pragma unroll
    for (int i = 0; i < 4; ++i) {
        v[i] = p[(size_t)(seg * 4 + i) * D4];
        sum = f4add(sum, v[i]);
    }
    part[c][seg] = sum;
    __syncthreads();
    if (threadIdx.x < 8) {
        float4 run = make_float4(0.f, 0.f, 0.f, 0.f);
#pragma unroll
        for (int s = 0; s < 32; ++s) {
            float4 t2 = part[threadIdx.x][s];
            part[threadIdx.x][s] = run;
            run = f4add(run, t2);
        }
    }
    __syncthreads();
    float4 run = part[c][seg];
    float4* o = O4 + (size_t)b * (NCH + 1) * D4 + col;
#pragma unroll
    for (int i = 0; i < 4; ++i) {
        o[(size_t)(seg * 4 + i) * D4] = run;
        run = f4add(run, v[i]);
    }
    if (seg == 31) o[(size_t)NCH * D4] = run;  // grand total = c[N]
}

// ---------------- K3: branchless batched gather ----------------
__global__ __launch_bounds__(256)
void k3_gather(const float4* __restrict__ x4, const float4* __restrict__ Wl4,
               const float4* __restrict__ O4, const int* __restrict__ graph,
               float4* __restrict__ out4) {
    const int t  = threadIdx.x;
    const int kt = blockIdx.x;                 // 0..511
    const int b  = blockIdx.y;

    // 2 steps' (s,e) as one uniform 16B load (broadcast; no LDS, no sync)
    const int4 g2 = *reinterpret_cast<const int4*>(
        graph + ((size_t)(b * STEPS + kt * KT)) * 2);
    const int sA[KT] = {g2.x, g2.z};
    const int eA[KT] = {g2.y, g2.w};

    const float4* xb = x4  + (size_t)b * Nn * D4 + t;
    const float4* wl = Wl4 + (size_t)b * STEPS * D4 + t;
    const float4* oc = O4  + (size_t)b * (NCH + 1) * D4 + t;
    float4*       ob = out4 + (size_t)b * 2 * STEPS * D4 + t;

    // ---- issue ALL loads before any combine ----
    float4 o1[KT], w1[KT], xs0[KT], xs1[KT];
    float4 o2[KT], w2[KT], xe0[KT], xe1[KT];
    int r1[KT], r2[KT], ieA[KT];
    float4 tot = oc[(size_t)NCH * D4];          // grand-total row (L2/L3-warm)
#pragma unroll
    for (int u = 0; u < KT; ++u) {
        int s  = sA[u];
        int m1 = s / 3;          r1[u] = s - 3 * m1;       // m1 <= 1023
        o1[u]  = oc[(size_t)(m1 >> 3) * D4];
        w1[u]  = wl[(size_t)m1 * D4];
        xs0[u] = xb[(size_t)(3 * m1) * D4];
        xs1[u] = xb[(size_t)(3 * m1 + 1) * D4];

        int ie = eA[u] + 1;      ieA[u] = ie;              // 1..3072
        int m2 = ie / 3;         r2[u] = ie - 3 * m2;
        int mc = m2 < STEPS - 1 ? m2 : STEPS - 1;          // clamp: always valid
        o2[u]  = oc[(size_t)(mc >> 3) * D4];
        w2[u]  = wl[(size_t)mc * D4];
        xe0[u] = xb[(size_t)(3 * mc) * D4];
        xe1[u] = xb[(size_t)(3 * mc + 1) * D4];
    }

    // ---- combine + store ----
    const float4 z4 = make_float4(0.f, 0.f, 0.f, 0.f);
#pragma unroll
    for (int u = 0; u < KT; ++u) {
        float4 cs = f4add(f4add(o1[u], w1[u]),
                          f4add(f4sel(r1[u] > 0, xs0[u], z4),
                                f4sel(r1[u] > 1, xs1[u], z4)));
        float4 ceN = f4add(f4add(o2[u], w2[u]),
                           f4add(f4sel(r2[u] > 0, xe0[u], z4),
                                 f4sel(r2[u] > 1, xe1[u], z4)));
        float4 ce = f4sel(ieA[u] == Nn, tot, ceN);

        float inv = 1.f / (float)(eA[u] - sA[u] + 1);
        float4 res = make_float4((ce.x - cs.x) * inv + EPS,
                                 (ce.y - cs.y) * inv + EPS,
                                 (ce.z - cs.z) * inv + EPS,
                                 (ce.w - cs.w) * inv + EPS);
        int k = kt * KT + u;
        nt_store(res, &ob[(size_t)(2 * k) * D4]);   // even output row
    }
}

extern "C" void kernel_launch(void* const* d_in, const int* in_sizes, int n_in,
                              void* d_out, int out_size, void* d_ws, size_t ws_size,
                              hipStream_t stream) {
    const float* x     = (const float*)d_in[0];
    const int*   graph = (const int*)d_in[1];
    float*       out   = (float*)d_out;

    float* Wl = (float*)d_ws;
    float* P  = Wl + WL_E;
    float* O  = P + P_E;

    dim3 g1(NCH, Bdim);          // (128, 8) = 1024 blocks
    k1_scan<<<g1, 256, 0, stream>>>((const float4*)x, (float4*)out,
                                    (float4*)Wl, (float4*)P);
    dim3 g2(D4 / 8, Bdim);       // (32, 8) = 256 blocks
    k2_chscan<<<g2, 256, 0, stream>>>((const float4*)P, (float4*)O);
    dim3 g3(NKT, Bdim);          // (512, 8) = 4096 blocks
    k3_gather<<<g3, 256, 0, stream>>>((const float4*)x, (const float4*)Wl,
                                      (const float4*)O, graph, (float4*)out);
}

// Round 3
// 194.975 us; speedup vs baseline: 1.0587x; 1.0587x over previous
//
#include <hip/hip_runtime.h>

// GraphPooling: B=8, N=3072, D=1024, POOL=3, steps=1024
//  out[b, 2k,   d] = (sum x[b, s..e, d]) / (e-s+1) + 0.006
//  out[b, 2k+1, d] = mean(x[b, 3k:3k+3, d])
//
// Round-10: row-granularity prefix (R) scheme.
//  - R2 regression post-mortem: regular x loads in K1 hurt (nt was a
//    measured win from the prior session; MALL caches fills regardless,
//    so K3's x gathers were already L3-served). Reverted: K1 nt x-loads,
//    K2 64-block proven version.
//  - NEW: K1 stores the within-chunk EXCLUSIVE prefix for EVERY row
//    (R[b,n,d], 96 MB) instead of only window boundaries (Wl, 32 MB).
//    C[n] = O[n/24] + R[n] exactly -> K3 reads just 2 random R rows +
//    2 L2-hot O rows per step (was 8 rows: O,Wl,2x raw-x per endpoint),
//    no residual selects. K3 request traffic 192 -> 96 MB; KT 2 -> 4.
//    Same summation order as before => identical numerics.

constexpr int Bdim  = 8;
constexpr int Nn    = 3072;
constexpr int Dd    = 1024;
constexpr int STEPS = 1024;   // windows
constexpr int CHW   = 8;      // windows per chunk
constexpr int CHR   = 24;     // rows per chunk
constexpr int NCH   = 128;    // STEPS / CHW
constexpr int KT    = 4;      // steps per K3 block
constexpr int NKT   = 256;    // STEPS / KT
constexpr int D4    = Dd / 4; // 256 float4 per row
constexpr float EPS = 0.006f;

constexpr size_t R_E = (size_t)Bdim * Nn * Dd;            // 96 MB (floats)
constexpr size_t P_E = (size_t)Bdim * NCH * Dd;           //  4 MB

typedef float nat_f4 __attribute__((ext_vector_type(4)));

__device__ __forceinline__ float4 f4add(float4 a, float4 b) {
    return make_float4(a.x + b.x, a.y + b.y, a.z + b.z, a.w + b.w);
}

__device__ __forceinline__ float4 f4sel(bool c, float4 a, float4 b) {
    return make_float4(c ? a.x : b.x, c ? a.y : b.y,
                       c ? a.z : b.z, c ? a.w : b.w);
}

__device__ __forceinline__ void nt_store(float4 v, float4* p) {
    nat_f4 nv = {v.x, v.y, v.z, v.w};
    __builtin_nontemporal_store(nv, reinterpret_cast<nat_f4*>(p));
}

__device__ __forceinline__ float4 nt_load(const float4* p) {
    nat_f4 nv = __builtin_nontemporal_load(reinterpret_cast<const nat_f4*>(p));
    return make_float4(nv.x, nv.y, nv.z, nv.w);
}

// ---------------- K1: window means + per-row within-chunk prefix ----------
__global__ __launch_bounds__(256)
void k1_scan(const float4* __restrict__ x4, float4* __restrict__ out4,
             float4* __restrict__ R4, float4* __restrict__ P4) {
    const int t  = threadIdx.x;          // float4 column 0..255
    const int ch = blockIdx.x;           // 0..127
    const int b  = blockIdx.y;           // 0..7
    const int k0 = ch * CHW;
    const int r0 = ch * CHR;

    const float4* xp = x4   + ((size_t)(b * Nn + r0)) * D4 + t;
    float4*       rl = R4   + ((size_t)(b * Nn + r0)) * D4 + t;
    float4*       op = out4 + ((size_t)b * 2 * STEPS) * D4 + t;

    // phase A: issue all 24 x loads (nt: streamed once, proven faster;
    // MALL caches the fill regardless, and K3 no longer reads x at all)
    float4 v[CHR];
#pragma unroll
    for (int i = 0; i < CHR; ++i)
        v[i] = nt_load(&xp[(size_t)i * D4]);

    // phase B: window means -> odd output rows
#pragma unroll
    for (int wi = 0; wi < CHW; ++wi) {
        float4 w = f4add(f4add(v[3 * wi], v[3 * wi + 1]), v[3 * wi + 2]);
        float4 wm = make_float4(w.x * (1.f / 3.f), w.y * (1.f / 3.f),
                                w.z * (1.f / 3.f), w.w * (1.f / 3.f));
        nt_store(wm, &op[(size_t)(2 * (k0 + wi) + 1) * D4]);
    }

    // phase C: exclusive within-chunk prefix for EVERY row (regular
    // stores: K3 re-reads these -> keep cache-resident)
    float4 run = make_float4(0.f, 0.f, 0.f, 0.f);
#pragma unroll
    for (int i = 0; i < CHR; ++i) {
        rl[(size_t)i * D4] = run;
        run = f4add(run, v[i]);
    }
    P4[((size_t)b * NCH + ch) * D4 + t] = run;   // chunk total
}

// ---------------- K2: 2-level scan of chunk totals -> exclusive prefix O ----
// (proven 64-block version from the 192.6 us baseline)
__global__ __launch_bounds__(256)
void k2_chscan(const float4* __restrict__ P4, float4* __restrict__ O4) {
    __shared__ float4 part[8][33];
    const int cw  = threadIdx.x & 31;          // f4-col within tile
    const int seg = threadIdx.x >> 5;          // 0..7 -> 16 chunks each
    const int col = blockIdx.x * 32 + cw;
    const int b   = blockIdx.y;

    const float4* p = P4 + (size_t)b * NCH * D4 + col;
    float4 v[16];
    float4 sum = make_float4(0.f, 0.f, 0.f, 0.f);
#pragma unroll
    for (int i = 0; i < 16; ++i) {
        v[i] = p[(size_t)(seg * 16 + i) * D4];
        sum = f4add(sum, v[i]);
    }
    part[seg][cw] = sum;
    __syncthreads();
    if (threadIdx.x < 32) {
        float4 run = make_float4(0.f, 0.f, 0.f, 0.f);
#pragma unroll
        for (int s = 0; s < 8; ++s) {
            float4 t2 = part[s][threadIdx.x];
            part[s][threadIdx.x] = run;
            run = f4add(run, t2);
        }
    }
    __syncthreads();
    float4 run = part[seg][cw];
    float4* o = O4 + (size_t)b * (NCH + 1) * D4 + col;
#pragma unroll
    for (int i = 0; i < 16; ++i) {
        o[(size_t)(seg * 16 + i) * D4] = run;
        run = f4add(run, v[i]);
    }
    if (seg == 7) o[(size_t)NCH * D4] = run;   // grand total = c[N]
}

// ---------------- K3: 2-row gather per step ----------------
// C[n] = O[n/24] + R[n];  seg_sum = C[e+1] - C[s]
__global__ __launch_bounds__(256)
void k3_gather(const float4* __restrict__ R4, const float4* __restrict__ O4,
               const int* __restrict__ graph, float4* __restrict__ out4) {
    const int t  = threadIdx.x;
    const int kt = blockIdx.x;                 // 0..255
    const int b  = blockIdx.y;

    // 4 steps' (s,e) as two uniform 16B loads (broadcast; no LDS, no sync)
    const int* gp = graph + ((size_t)(b * STEPS + kt * KT)) * 2;
    const int4 ga = *reinterpret_cast<const int4*>(gp);
    const int4 gb = *reinterpret_cast<const int4*>(gp + 4);
    const int sA[KT] = {ga.x, ga.z, gb.x, gb.z};
    const int eA[KT] = {ga.y, ga.w, gb.y, gb.w};

    const float4* rb = R4  + (size_t)b * Nn * D4 + t;
    const float4* oc = O4  + (size_t)b * (NCH + 1) * D4 + t;
    float4*       ob = out4 + (size_t)b * 2 * STEPS * D4 + t;

    // ---- issue ALL loads before any combine ----
    float4 o1[KT], r1[KT], o2[KT], r2[KT];
    int ieA[KT];
#pragma unroll
    for (int u = 0; u < KT; ++u) {
        int s  = sA[u];
        int c1 = s / CHR;                          // 0..127
        o1[u] = oc[(size_t)c1 * D4];               // L2/L3-hot (4.2 MB table)
        r1[u] = rb[(size_t)s * D4];                // random 4 KB row

        int ie = eA[u] + 1;      ieA[u] = ie;      // 1..3072
        int c2 = ie / CHR;                         // 0..128 (O[128]=grand tot)
        o2[u] = oc[(size_t)c2 * D4];
        int rc = ie < Nn ? ie : Nn - 1;            // clamp: always valid
        r2[u] = rb[(size_t)rc * D4];
    }

    // ---- combine + store ----
    const float4 z4 = make_float4(0.f, 0.f, 0.f, 0.f);
#pragma unroll
    for (int u = 0; u < KT; ++u) {
        float4 cs = f4add(o1[u], r1[u]);
        float4 ce = f4add(o2[u], f4sel(ieA[u] < Nn, r2[u], z4));

        float inv = 1.f / (float)(eA[u] - sA[u] + 1);
        float4 res = make_float4((ce.x - cs.x) * inv + EPS,
                                 (ce.y - cs.y) * inv + EPS,
                                 (ce.z - cs.z) * inv + EPS,
                                 (ce.w - cs.w) * inv + EPS);
        int k = kt * KT + u;
        nt_store(res, &ob[(size_t)(2 * k) * D4]);   // even output row
    }
}

extern "C" void kernel_launch(void* const* d_in, const int* in_sizes, int n_in,
                              void* d_out, int out_size, void* d_ws, size_t ws_size,
                              hipStream_t stream) {
    const float* x     = (const float*)d_in[0];
    const int*   graph = (const int*)d_in[1];
    float*       out   = (float*)d_out;

    float* R = (float*)d_ws;
    float* P = R + R_E;
    float* O = P + P_E;

    dim3 g1(NCH, Bdim);          // (128, 8) = 1024 blocks
    k1_scan<<<g1, 256, 0, stream>>>((const float4*)x, (float4*)out,
                                    (float4*)R, (float4*)P);
    dim3 g2(D4 / 32, Bdim);      // (8, 8) = 64 blocks
    k2_chscan<<<g2, 256, 0, stream>>>((const float4*)P, (float4*)O);
    dim3 g3(NKT, Bdim);          // (256, 8) = 2048 blocks
    k3_gather<<<g3, 256, 0, stream>>>((const float4*)R, (const float4*)O,
                                      graph, (float4*)out);
}